// Round 2
// baseline (3265.308 us; speedup 1.0000x reference)
//
#include <hip/hip_runtime.h>
#include <hip/hip_bf16.h>
#include <math.h>

#define LL 4096

typedef __attribute__((ext_vector_type(8))) short short8;
typedef __attribute__((ext_vector_type(8))) unsigned short us8;
typedef __attribute__((ext_vector_type(4))) float f32x4;
typedef __attribute__((ext_vector_type(4))) unsigned short us4;

__device__ __forceinline__ unsigned short bf16_rn(float f) {
  unsigned u = __float_as_uint(f);
  u = u + 0x7FFFu + ((u >> 16) & 1u);
  return (unsigned short)(u >> 16);
}
__device__ __forceinline__ float bf16_f(unsigned short h) {
  return __uint_as_float(((unsigned)h) << 16);
}
// tanh(x) = 1 - 2/(e^{2x}+1); |x| < 40 safe. ~5 VALU ops vs ~30 for tanhf.
__device__ __forceinline__ float ftanh(float x) {
  float e = __builtin_amdgcn_exp2f(x * 2.885390081777927f);  // 2*log2(e)
  return 1.0f - 2.0f * __builtin_amdgcn_rcpf(e + 1.0f);
}

// ---------------------------------------------------------------------------
// Prep: pack Wq/Wk/Wv (f32 [512][512], W[e][d], K-contiguous) into MFMA-B-
// fragment-ready bf16 hi/lo arrays.
// value W[e = fn*16 + (lane&15)][d = kt*32 + (lane>>4)*8 + j]
//   at ushort index ((fn*16 + kt)*64 + lane)*8 + j.
// Per matrix: hi at mat*524288, lo at +262144. mat: 0=Q,1=K,2=V.
// ---------------------------------------------------------------------------
__global__ void prep_kernel(const float* __restrict__ Wq,
                            const float* __restrict__ Wk,
                            const float* __restrict__ Wv,
                            unsigned short* __restrict__ ws_u16) {
  int id = blockIdx.x * blockDim.x + threadIdx.x;  // 0..98303
  int mat = id >> 15;
  int rem = id & 32767;
  int fn = rem >> 10;
  int kt = (rem >> 6) & 15;
  int ln = rem & 63;
  int e  = fn * 16 + (ln & 15);
  int d0 = kt * 32 + ((ln >> 4) << 3);
  const float* W = (mat == 0) ? Wq : (mat == 1) ? Wk : Wv;
  unsigned short* oh = ws_u16 + (size_t)mat * 524288 + (size_t)rem * 8;
  unsigned short* ol = oh + 262144;
  const float* src = W + (size_t)e * 512 + d0;
#pragma unroll
  for (int j = 0; j < 8; ++j) {
    float f = src[j];
    unsigned short h = bf16_rn(f);
    oh[j] = h;
    ol[j] = bf16_rn(f - bf16_f(h));
  }
}

// ---- staging helpers (convert f32 -> bf16 hi/lo, write LDS) ----
#define STAGE128(HB, LB, V0, V1)                                        \
  {                                                                     \
    us8 h_, l_;                                                         \
    float tf[8] = {(V0).x, (V0).y, (V0).z, (V0).w,                      \
                   (V1).x, (V1).y, (V1).z, (V1).w};                     \
    _Pragma("unroll")                                                   \
    for (int j = 0; j < 8; ++j) {                                       \
      unsigned short hh = bf16_rn(tf[j]);                               \
      h_[j] = hh;                                                       \
      l_[j] = bf16_rn(tf[j] - bf16_f(hh));                              \
    }                                                                   \
    *(us8*)&(HB)[r0 * 40 + c8] = h_;                                    \
    *(us8*)&(LB)[r0 * 40 + c8] = l_;                                    \
  }

#define STAGE64(HB, LB, V)                                              \
  {                                                                     \
    us4 h_, l_;                                                         \
    float tf[4] = {(V).x, (V).y, (V).z, (V).w};                         \
    _Pragma("unroll")                                                   \
    for (int j = 0; j < 4; ++j) {                                       \
      unsigned short hh = bf16_rn(tf[j]);                               \
      h_[j] = hh;                                                       \
      l_[j] = bf16_rn(tf[j] - bf16_f(hh));                              \
    }                                                                   \
    *(us4*)&(HB)[r0 * 40 + c4] = h_;                                    \
    *(us4*)&(LB)[r0 * 40 + c4] = l_;                                    \
  }

// ---------------------------------------------------------------------------
// Pass 1: Q path. pre = x.Wq^T (split bf16 hi/lo, 3 MFMA), colsum of
// tanh(pre+bq) -> qpart[block][512]. Block = 128 rows x 512 cols, 8 waves
// 1M x 8N (each wave owns 64 distinct cols -> no redundant B loads).
// Double-buffered LDS x-tile + register-double-buffered B frags.
// ---------------------------------------------------------------------------
__global__ __launch_bounds__(512, 4) void pass1_q(
    const float* __restrict__ x,
    const unsigned short* __restrict__ wf_hi,
    const unsigned short* __restrict__ wf_lo,
    const float* __restrict__ bias,
    float* __restrict__ qpart) {
  __shared__ unsigned short hib[2][128 * 40];   // stride 40 ushorts (80B)
  __shared__ unsigned short lob[2][128 * 40];

  const int tid = threadIdx.x;
  const int lane = tid & 63;
  const int w = tid >> 6;
  const int l15 = lane & 15, ks = lane >> 4;
  const int r0 = tid >> 2, c8 = (tid & 3) * 8;  // staging: 8 floats/thread
  const float* gx = x + (size_t)blockIdx.x * 128 * 512;
  const float* gxr = gx + (size_t)r0 * 512 + c8;

  const int abase = l15 * 40 + ks * 8;  // A-frag ushort offset, + m*640
  const unsigned short* bhp = wf_hi + w * 32768 + lane * 8;
  const unsigned short* blp = wf_lo + w * 32768 + lane * 8;

  f32x4 acc[8][4] = {};
  short8 ah[8], al[8];
  short8 BhA[4], BlA[4], BhB[4], BlB[4];
  float4 XA0, XA1, XB0, XB1;

#define P1_BODY(KT, I, BHC, BLC, BHN, BLN, XV0, XV1, XN0, XN1)            \
  {                                                                       \
    const int ktb = (KT) + 1 > 15 ? 15 : (KT) + 1;                        \
    const int ktx = (KT) + 2 > 15 ? 15 : (KT) + 2;                        \
    _Pragma("unroll")                                                     \
    for (int f = 0; f < 4; ++f) {                                         \
      BHN[f] = *(const short8*)(bhp + f * 8192 + ktb * 512);              \
      BLN[f] = *(const short8*)(blp + f * 8192 + ktb * 512);              \
    }                                                                     \
    XN0 = *(const float4*)(gxr + ktx * 32);                               \
    XN1 = *(const float4*)(gxr + ktx * 32 + 4);                           \
    _Pragma("unroll")                                                     \
    for (int m = 0; m < 8; ++m) {                                         \
      ah[m] = *(const short8*)(&hib[I][abase + m * 640]);                 \
      al[m] = *(const short8*)(&lob[I][abase + m * 640]);                 \
    }                                                                     \
    if ((KT) < 15) { STAGE128(hib[(I) ^ 1], lob[(I) ^ 1], XV0, XV1); }    \
    _Pragma("unroll")                                                     \
    for (int f = 0; f < 4; ++f) {                                         \
      _Pragma("unroll")                                                   \
      for (int m = 0; m < 8; ++m) {                                       \
        acc[m][f] = __builtin_amdgcn_mfma_f32_16x16x32_bf16(ah[m], BHC[f], acc[m][f], 0, 0, 0); \
        acc[m][f] = __builtin_amdgcn_mfma_f32_16x16x32_bf16(al[m], BHC[f], acc[m][f], 0, 0, 0); \
        acc[m][f] = __builtin_amdgcn_mfma_f32_16x16x32_bf16(ah[m], BLC[f], acc[m][f], 0, 0, 0); \
      }                                                                   \
    }                                                                     \
    __syncthreads();                                                      \
  }

  // prologue
  XA0 = *(const float4*)(gxr);
  XA1 = *(const float4*)(gxr + 4);
#pragma unroll
  for (int f = 0; f < 4; ++f) {
    BhA[f] = *(const short8*)(bhp + f * 8192);
    BlA[f] = *(const short8*)(blp + f * 8192);
  }
  STAGE128(hib[0], lob[0], XA0, XA1);
  XA0 = *(const float4*)(gxr + 32);
  XA1 = *(const float4*)(gxr + 36);
  __syncthreads();

#pragma unroll 1
  for (int kt = 0; kt < 16; kt += 2) {
    P1_BODY(kt, 0, BhA, BlA, BhB, BlB, XA0, XA1, XB0, XB1)
    P1_BODY(kt + 1, 1, BhB, BlB, BhA, BlA, XB0, XB1, XA0, XA1)
  }
#undef P1_BODY

  // epilogue: C/D layout col = lane&15, row = (lane>>4)*4 + i  [verified]
  float cs[4];
#pragma unroll
  for (int f = 0; f < 4; ++f) {
    float bc = bias[w * 64 + f * 16 + l15];
    float s = 0.f;
#pragma unroll
    for (int m = 0; m < 8; ++m)
#pragma unroll
      for (int i = 0; i < 4; ++i)
        s += ftanh(acc[m][f][i] + bc);
    cs[f] = s;
  }
#pragma unroll
  for (int f = 0; f < 4; ++f) {
    cs[f] += __shfl_xor(cs[f], 16);
    cs[f] += __shfl_xor(cs[f], 32);
  }
  if (lane < 16) {
#pragma unroll
    for (int f = 0; f < 4; ++f)
      qpart[(size_t)blockIdx.x * 512 + w * 64 + f * 16 + lane] = cs[f];
  }
}

// ---------------------------------------------------------------------------
// Pass 2: K (split, weighted rowsum by q_sum) + V (single, rowsum) fused,
// sharing x staging and A-frags. Block = 64 rows x 512 cols, 8 waves 1Mx8N.
// ---------------------------------------------------------------------------
__global__ __launch_bounds__(512, 4) void pass2_kv(
    const float* __restrict__ x,
    const unsigned short* __restrict__ kh,
    const unsigned short* __restrict__ kl,
    const unsigned short* __restrict__ vh,
    const float* __restrict__ bk,
    const float* __restrict__ bv,
    const float* __restrict__ q_sum,
    float* __restrict__ scores,
    float* __restrict__ sv) {
  __shared__ unsigned short hib[2][64 * 40];
  __shared__ unsigned short lob[2][64 * 40];
  __shared__ float redk[8][64];
  __shared__ float redv[8][64];

  const int tid = threadIdx.x;
  const int lane = tid & 63;
  const int w = tid >> 6;
  const int l15 = lane & 15, ks = lane >> 4;
  const int r0 = tid >> 3, c4 = (tid & 7) * 4;  // staging: 4 floats/thread
  const float* gx = x + (size_t)blockIdx.x * 64 * 512;
  const float* gxr = gx + (size_t)r0 * 512 + c4;

  const int abase = l15 * 40 + ks * 8;
  const unsigned short* khp = kh + w * 32768 + lane * 8;
  const unsigned short* klp = kl + w * 32768 + lane * 8;
  const unsigned short* vhp = vh + w * 32768 + lane * 8;

  f32x4 acck[4][4] = {};
  f32x4 accv[4][4] = {};
  short8 ah[4], al[4];
  short8 KhA[4], KlA[4], VhA[4], KhB[4], KlB[4], VhB[4];
  float4 XA, XB;

#define P2_BODY(KT, I, KHC, KLC, VHC, KHN, KLN, VHN, XV, XN)              \
  {                                                                       \
    const int ktb = (KT) + 1 > 15 ? 15 : (KT) + 1;                        \
    const int ktx = (KT) + 2 > 15 ? 15 : (KT) + 2;                        \
    _Pragma("unroll")                                                     \
    for (int f = 0; f < 4; ++f) {                                         \
      KHN[f] = *(const short8*)(khp + f * 8192 + ktb * 512);              \
      KLN[f] = *(const short8*)(klp + f * 8192 + ktb * 512);              \
      VHN[f] = *(const short8*)(vhp + f * 8192 + ktb * 512);              \
    }                                                                     \
    XN = *(const float4*)(gxr + ktx * 32);                                \
    _Pragma("unroll")                                                     \
    for (int m = 0; m < 4; ++m) {                                         \
      ah[m] = *(const short8*)(&hib[I][abase + m * 640]);                 \
      al[m] = *(const short8*)(&lob[I][abase + m * 640]);                 \
    }                                                                     \
    if ((KT) < 15) { STAGE64(hib[(I) ^ 1], lob[(I) ^ 1], XV); }           \
    _Pragma("unroll")                                                     \
    for (int f = 0; f < 4; ++f) {                                         \
      _Pragma("unroll")                                                   \
      for (int m = 0; m < 4; ++m) {                                       \
        acck[m][f] = __builtin_amdgcn_mfma_f32_16x16x32_bf16(ah[m], KHC[f], acck[m][f], 0, 0, 0); \
        acck[m][f] = __builtin_amdgcn_mfma_f32_16x16x32_bf16(al[m], KHC[f], acck[m][f], 0, 0, 0); \
        acck[m][f] = __builtin_amdgcn_mfma_f32_16x16x32_bf16(ah[m], KLC[f], acck[m][f], 0, 0, 0); \
        accv[m][f] = __builtin_amdgcn_mfma_f32_16x16x32_bf16(ah[m], VHC[f], accv[m][f], 0, 0, 0); \
      }                                                                   \
    }                                                                     \
    __syncthreads();                                                      \
  }

  // prologue
  XA = *(const float4*)(gxr);
#pragma unroll
  for (int f = 0; f < 4; ++f) {
    KhA[f] = *(const short8*)(khp + f * 8192);
    KlA[f] = *(const short8*)(klp + f * 8192);
    VhA[f] = *(const short8*)(vhp + f * 8192);
  }
  STAGE64(hib[0], lob[0], XA);
  XA = *(const float4*)(gxr + 32);
  __syncthreads();

#pragma unroll 1
  for (int kt = 0; kt < 16; kt += 2) {
    P2_BODY(kt, 0, KhA, KlA, VhA, KhB, KlB, VhB, XA, XB)
    P2_BODY(kt + 1, 1, KhB, KlB, VhB, KhA, KlA, VhA, XB, XA)
  }
#undef P2_BODY

  // epilogue
  const int b = blockIdx.x >> 6;
  float sk[4][4] = {};
  float s_v[4][4] = {};
#pragma unroll
  for (int f = 0; f < 4; ++f) {
    int c = w * 64 + f * 16 + l15;
    float qs = q_sum[b * 512 + c];
    float bkc = bk[c], bvc = bv[c];
#pragma unroll
    for (int m = 0; m < 4; ++m)
#pragma unroll
      for (int i = 0; i < 4; ++i) {
        sk[m][i] += ftanh(acck[m][f][i] + bkc) * qs;
        s_v[m][i] += ftanh(accv[m][f][i] + bvc);
      }
  }
#pragma unroll
  for (int m = 0; m < 4; ++m)
#pragma unroll
    for (int i = 0; i < 4; ++i) {
#pragma unroll
      for (int off = 1; off <= 8; off <<= 1) {
        sk[m][i] += __shfl_xor(sk[m][i], off);
        s_v[m][i] += __shfl_xor(s_v[m][i], off);
      }
    }
  if (l15 == 0) {
#pragma unroll
    for (int m = 0; m < 4; ++m)
#pragma unroll
      for (int i = 0; i < 4; ++i) {
        redk[w][m * 16 + ks * 4 + i] = sk[m][i];
        redv[w][m * 16 + ks * 4 + i] = s_v[m][i];
      }
  }
  __syncthreads();
  if (tid < 64) {
    float s = 0.f;
#pragma unroll
    for (int j = 0; j < 8; ++j) s += redk[j][tid];
    scores[(size_t)blockIdx.x * 64 + tid] = s;
  } else if (tid < 128) {
    int r = tid - 64;
    float s = 0.f;
#pragma unroll
    for (int j = 0; j < 8; ++j) s += redv[j][r];
    sv[(size_t)blockIdx.x * 64 + r] = s;
  }
}

// q_sum[b][e] = sum of the batch's 32 row-block partials (BM=128 -> 32/batch)
__global__ void reduce_q(const float* __restrict__ qpart, float* __restrict__ q_sum) {
  int b = blockIdx.x;
  int e = threadIdx.x;
  const float* p = qpart + (size_t)b * 32 * 512 + e;
  float s = 0.f;
#pragma unroll
  for (int j = 0; j < 32; ++j) s += p[j * 512];
  q_sum[b * 512 + e] = s;
}

// per-batch masked softmax over scaled scores, times sv
__global__ void softmax_out(const float* __restrict__ scores,
                            const float* __restrict__ sv,
                            const int* __restrict__ lens,
                            float* __restrict__ out) {
  const int b = blockIdx.x;
  const int tid = threadIdx.x;  // 256
  const int lane = tid & 63, wid = tid >> 6;
  const int len = lens[b];
  const float scale = 0.04419417382415922f;  // 1/sqrt(512)
  __shared__ float sb[4];
  __shared__ float sb2[4];

  float sreg[16];
  const float* sc = scores + (size_t)b * LL;
#pragma unroll
  for (int j = 0; j < 16; ++j) sreg[j] = sc[tid + j * 256] * scale;

  float m = -1e30f;
#pragma unroll
  for (int j = 0; j < 16; ++j)
    if (tid + j * 256 < len) m = fmaxf(m, sreg[j]);
#pragma unroll
  for (int off = 32; off >= 1; off >>= 1) m = fmaxf(m, __shfl_xor(m, off));
  if (lane == 0) sb[wid] = m;
  __syncthreads();
  m = fmaxf(fmaxf(sb[0], sb[1]), fmaxf(sb[2], sb[3]));

  float s = 0.f;
#pragma unroll
  for (int j = 0; j < 16; ++j)
    if (tid + j * 256 < len) s += expf(sreg[j] - m);
#pragma unroll
  for (int off = 32; off >= 1; off >>= 1) s += __shfl_xor(s, off);
  if (lane == 0) sb2[wid] = s;
  __syncthreads();
  const float inv = 1.f / (sb2[0] + sb2[1] + sb2[2] + sb2[3]);

  const float* svb = sv + (size_t)b * LL;
  float* ob = out + (size_t)b * LL;
#pragma unroll
  for (int j = 0; j < 16; ++j) {
    int l = tid + j * 256;
    ob[l] = (l < len) ? svb[l] * expf(sreg[j] - m) * inv : 0.0f;
  }
}

extern "C" void kernel_launch(void* const* d_in, const int* in_sizes, int n_in,
                              void* d_out, int out_size, void* d_ws, size_t ws_size,
                              hipStream_t stream) {
  const float* x  = (const float*)d_in[0];
  const float* Wk = (const float*)d_in[1];
  const float* bk = (const float*)d_in[2];
  const float* Wq = (const float*)d_in[3];
  const float* bq = (const float*)d_in[4];
  const float* Wv = (const float*)d_in[5];
  const float* bv = (const float*)d_in[6];
  const int* lens = (const int*)d_in[7];
  float* out = (float*)d_out;

  char* ws = (char*)d_ws;
  unsigned short* wfu = (unsigned short*)ws;
  const size_t WQ_HI = 0, WQ_LO = 262144;
  const size_t WK_HI = 524288, WK_LO = 786432;
  const size_t WV_HI = 1048576;
  float* qpart  = (float*)(ws + 3u * 1024 * 1024);                   // [512][512]
  float* q_sum  = (float*)(ws + 5u * 1024 * 1024);                   // [16][512]
  float* sv     = (float*)(ws + 5u * 1024 * 1024 + 32768);           // [16][4096]
  float* scores = (float*)(ws + 5u * 1024 * 1024 + 32768 + 262144);  // [16][4096]

  prep_kernel<<<384, 256, 0, stream>>>(Wq, Wk, Wv, wfu);
  pass1_q<<<512, 512, 0, stream>>>(x, wfu + WQ_HI, wfu + WQ_LO, bq, qpart);
  reduce_q<<<16, 512, 0, stream>>>(qpart, q_sum);
  pass2_kv<<<1024, 512, 0, stream>>>(x, wfu + WK_HI, wfu + WK_LO, wfu + WV_HI,
                                     bk, bv, q_sum, scores, sv);
  softmax_out<<<16, 256, 0, stream>>>(scores, sv, lens, out);
}

// Round 3
// 271.932 us; speedup vs baseline: 12.0078x; 12.0078x over previous
//
#include <hip/hip_runtime.h>
#include <hip/hip_bf16.h>
#include <math.h>

typedef __attribute__((ext_vector_type(8))) short short8;
typedef __attribute__((ext_vector_type(16))) float f32x16;
typedef __attribute__((ext_vector_type(4))) unsigned short us4;
typedef __attribute__((ext_vector_type(8))) unsigned short us8;

static __device__ __forceinline__ unsigned short bf16_rn(float f) {
  unsigned u = __float_as_uint(f);
  u += 0x7FFFu + ((u >> 16) & 1u);
  return (unsigned short)(u >> 16);
}
// split f into bf16 hi (round-nearest) + bf16 lo = rn(f - f32(hi)); hi+lo error ~2^-17
static __device__ __forceinline__ void cvt_hilo(float f, unsigned short& h, unsigned short& l) {
  unsigned u = __float_as_uint(f);
  unsigned hr = u + 0x7FFFu + ((u >> 16) & 1u);
  h = (unsigned short)(hr >> 16);
  l = bf16_rn(f - __uint_as_float(hr & 0xFFFF0000u));
}
// tanh(x) = 1 - 2/(e^{2x}+1); overflow-safe (exp->inf => 1, exp->0 => -1)
static __device__ __forceinline__ float ftanh(float x) {
  float e = __builtin_amdgcn_exp2f(x * 2.885390081777927f);
  return 1.0f - 2.0f * __builtin_amdgcn_rcpf(e + 1.0f);
}

// ---------------------------------------------------------------------------
// Prep: pack Wq/Wk/Wv (f32 [512][512], W[e][d], K-contiguous) into 32x32x16
// MFMA-B-fragment order, bf16 hi/lo.
// value W[e = fn*32 + (lane&31)][d = gk*16 + (lane>>5)*8 + j]
//   at ushort index ((fn*32 + gk)*64 + lane)*8 + j ; fn:0..15, gk:0..31.
// Per matrix: hi at mat*524288, lo at +262144. mat: 0=Q,1=K,2=V.
// ---------------------------------------------------------------------------
__global__ void prep_kernel(const float* __restrict__ Wq,
                            const float* __restrict__ Wk,
                            const float* __restrict__ Wv,
                            unsigned short* __restrict__ ws_u16) {
  int id = blockIdx.x * 256 + threadIdx.x;  // 0..98303
  int mat = id >> 15;
  int rem = id & 32767;
  int fn = rem >> 11;
  int gk = (rem >> 6) & 31;
  int ln = rem & 63;
  int e  = fn * 32 + (ln & 31);
  int d0 = gk * 16 + ((ln >> 5) << 3);
  const float* W = (mat == 0) ? Wq : (mat == 1) ? Wk : Wv;
  unsigned short* oh = ws_u16 + (size_t)mat * 524288 + (size_t)rem * 8;
  unsigned short* ol = oh + 262144;
  const float* src = W + (size_t)e * 512 + d0;
#pragma unroll
  for (int j = 0; j < 8; ++j) {
    unsigned short h, l;
    cvt_hilo(src[j], h, l);
    oh[j] = h;
    ol[j] = l;
  }
}

// ---------------------------------------------------------------------------
// Pass 1: Q path. 128 rows x 512 cols per block, 8 waves 1Mx8N, 32x32x16 MFMA,
// 3-term hi/lo split. Epilogue: colsum of tanh(pre+bq) -> qpart[block][512].
// ---------------------------------------------------------------------------
__global__ __launch_bounds__(512, 2) void pass1_q(
    const float* __restrict__ x,
    const unsigned short* __restrict__ bh,
    const unsigned short* __restrict__ bl,
    const float* __restrict__ bias,
    float* __restrict__ qpart) {
  __shared__ unsigned short hib[2][128 * 40];   // row stride 40 ushorts (80 B)
  __shared__ unsigned short lob[2][128 * 40];

  const int tid = threadIdx.x;
  const int lane = tid & 63;
  const int w = tid >> 6;
  const int l31 = lane & 31, hs = lane >> 5;
  const int sr = tid >> 2, sc = (tid & 3) * 8;      // staging: 8 floats/thread
  const float* gxr = x + (size_t)blockIdx.x * 128 * 512 + (size_t)sr * 512 + sc;

  const int aoff = l31 * 40 + hs * 8;               // + mt*1280 + ks*16
  const unsigned short* bhp = bh + (size_t)w * 16384 + (size_t)lane * 8;
  const unsigned short* blp = bl + (size_t)w * 16384 + (size_t)lane * 8;

  f32x16 acc[4][2] = {};

#define STAGE1(BUFI, V0, V1)                                        \
  {                                                                 \
    float tf[8] = {(V0).x, (V0).y, (V0).z, (V0).w,                  \
                   (V1).x, (V1).y, (V1).z, (V1).w};                 \
    us8 hv, lv;                                                     \
    _Pragma("unroll")                                               \
    for (int j = 0; j < 8; ++j) {                                   \
      unsigned short hh, ll;                                        \
      cvt_hilo(tf[j], hh, ll);                                      \
      hv[j] = hh; lv[j] = ll;                                       \
    }                                                               \
    *(us8*)&hib[BUFI][sr * 40 + sc] = hv;                           \
    *(us8*)&lob[BUFI][sr * 40 + sc] = lv;                           \
  }

  // prologue: stage chunk 0, prefetch chunk 1
  float4 xa0 = *(const float4*)(gxr);
  float4 xa1 = *(const float4*)(gxr + 4);
  STAGE1(0, xa0, xa1)
  float4 xb0 = *(const float4*)(gxr + 32);
  float4 xb1 = *(const float4*)(gxr + 36);
  __syncthreads();

#pragma unroll 1
  for (int c = 0; c < 16; ++c) {
    const int cur = c & 1;
    if (c < 15) { STAGE1(cur ^ 1, xb0, xb1) }       // stage chunk c+1
    if (c < 14) {                                   // prefetch chunk c+2
      xb0 = *(const float4*)(gxr + (c + 2) * 32);
      xb1 = *(const float4*)(gxr + (c + 2) * 32 + 4);
    }
    __syncthreads();

    short8 Bh[2][2], Bl[2][2];
#pragma unroll
    for (int ks = 0; ks < 2; ++ks)
#pragma unroll
      for (int nn = 0; nn < 2; ++nn) {
        const int go = nn * (8 * 16384) + (c * 2 + ks) * 512;
        Bh[ks][nn] = *(const short8*)(bhp + go);
        Bl[ks][nn] = *(const short8*)(blp + go);
      }
    const unsigned short* hc = &hib[cur][0];
    const unsigned short* lc = &lob[cur][0];
#pragma unroll
    for (int ks = 0; ks < 2; ++ks) {
      short8 ah[4], al[4];
#pragma unroll
      for (int mt = 0; mt < 4; ++mt) {
        ah[mt] = *(const short8*)(hc + aoff + mt * 1280 + ks * 16);
        al[mt] = *(const short8*)(lc + aoff + mt * 1280 + ks * 16);
      }
#pragma unroll
      for (int nn = 0; nn < 2; ++nn)
#pragma unroll
        for (int mt = 0; mt < 4; ++mt) {
          acc[mt][nn] = __builtin_amdgcn_mfma_f32_32x32x16_bf16(ah[mt], Bh[ks][nn], acc[mt][nn], 0, 0, 0);
          acc[mt][nn] = __builtin_amdgcn_mfma_f32_32x32x16_bf16(al[mt], Bh[ks][nn], acc[mt][nn], 0, 0, 0);
          acc[mt][nn] = __builtin_amdgcn_mfma_f32_32x32x16_bf16(ah[mt], Bl[ks][nn], acc[mt][nn], 0, 0, 0);
        }
    }
    __syncthreads();
  }
#undef STAGE1

  // epilogue: colsum of tanh. C/D: col=lane&31, rows covered by 16 regs x 2 halves.
  float cs[2];
#pragma unroll
  for (int nn = 0; nn < 2; ++nn) {
    float bc = bias[(w + 8 * nn) * 32 + l31];
    float s = 0.f;
#pragma unroll
    for (int mt = 0; mt < 4; ++mt)
#pragma unroll
      for (int r = 0; r < 16; ++r)
        s += ftanh(acc[mt][nn][r] + bc);
    s += __shfl_xor(s, 32);
    cs[nn] = s;
  }
  if (lane < 32) {
#pragma unroll
    for (int nn = 0; nn < 2; ++nn)
      qpart[(size_t)blockIdx.x * 512 + (w + 8 * nn) * 32 + l31] = cs[nn];
  }
}

// ---------------------------------------------------------------------------
// Pass 2: K (3-term split, rowsum weighted by q_sum) + V (1-term, rowsum),
// sharing x staging/A-frags. 64 rows x 512 cols, 8 waves 1Mx8N.
// ---------------------------------------------------------------------------
__global__ __launch_bounds__(512, 2) void pass2_kv(
    const float* __restrict__ x,
    const unsigned short* __restrict__ kh,
    const unsigned short* __restrict__ kl,
    const unsigned short* __restrict__ vh,
    const float* __restrict__ bk,
    const float* __restrict__ bv,
    const float* __restrict__ q_sum,
    float* __restrict__ scores,
    float* __restrict__ sv) {
  __shared__ unsigned short hib[2][64 * 40];
  __shared__ unsigned short lob[2][64 * 40];
  __shared__ float redk[8][64];
  __shared__ float redv[8][64];

  const int tid = threadIdx.x;
  const int lane = tid & 63;
  const int w = tid >> 6;
  const int l31 = lane & 31, hs = lane >> 5;
  const int sr = tid >> 3, sc = (tid & 7) * 4;      // staging: 4 floats/thread
  const float* gxr = x + (size_t)blockIdx.x * 64 * 512 + (size_t)sr * 512 + sc;

  const int aoff = l31 * 40 + hs * 8;               // + mt*1280 + ks*16
  const unsigned short* khp = kh + (size_t)w * 16384 + (size_t)lane * 8;
  const unsigned short* klp = kl + (size_t)w * 16384 + (size_t)lane * 8;
  const unsigned short* vhp = vh + (size_t)w * 16384 + (size_t)lane * 8;

  f32x16 acck[2][2] = {};
  f32x16 accv[2][2] = {};

#define STAGE2(BUFI, V)                                             \
  {                                                                 \
    float tf[4] = {(V).x, (V).y, (V).z, (V).w};                     \
    us4 hv, lv;                                                     \
    _Pragma("unroll")                                               \
    for (int j = 0; j < 4; ++j) {                                   \
      unsigned short hh, ll;                                        \
      cvt_hilo(tf[j], hh, ll);                                      \
      hv[j] = hh; lv[j] = ll;                                       \
    }                                                               \
    *(us4*)&hib[BUFI][sr * 40 + sc] = hv;                           \
    *(us4*)&lob[BUFI][sr * 40 + sc] = lv;                           \
  }

  float4 xa = *(const float4*)(gxr);
  STAGE2(0, xa)
  float4 xb = *(const float4*)(gxr + 32);
  __syncthreads();

#pragma unroll 1
  for (int c = 0; c < 16; ++c) {
    const int cur = c & 1;
    if (c < 15) { STAGE2(cur ^ 1, xb) }
    if (c < 14) { xb = *(const float4*)(gxr + (c + 2) * 32); }
    __syncthreads();

    short8 Kh[2][2], Kl[2][2], Vh[2][2];
#pragma unroll
    for (int ks = 0; ks < 2; ++ks)
#pragma unroll
      for (int nn = 0; nn < 2; ++nn) {
        const int go = nn * (8 * 16384) + (c * 2 + ks) * 512;
        Kh[ks][nn] = *(const short8*)(khp + go);
        Kl[ks][nn] = *(const short8*)(klp + go);
        Vh[ks][nn] = *(const short8*)(vhp + go);
      }
    const unsigned short* hc = &hib[cur][0];
    const unsigned short* lc = &lob[cur][0];
#pragma unroll
    for (int ks = 0; ks < 2; ++ks) {
      short8 ah[2], al[2];
#pragma unroll
      for (int mt = 0; mt < 2; ++mt) {
        ah[mt] = *(const short8*)(hc + aoff + mt * 1280 + ks * 16);
        al[mt] = *(const short8*)(lc + aoff + mt * 1280 + ks * 16);
      }
#pragma unroll
      for (int nn = 0; nn < 2; ++nn)
#pragma unroll
        for (int mt = 0; mt < 2; ++mt) {
          acck[mt][nn] = __builtin_amdgcn_mfma_f32_32x32x16_bf16(ah[mt], Kh[ks][nn], acck[mt][nn], 0, 0, 0);
          acck[mt][nn] = __builtin_amdgcn_mfma_f32_32x32x16_bf16(al[mt], Kh[ks][nn], acck[mt][nn], 0, 0, 0);
          acck[mt][nn] = __builtin_amdgcn_mfma_f32_32x32x16_bf16(ah[mt], Kl[ks][nn], acck[mt][nn], 0, 0, 0);
          accv[mt][nn] = __builtin_amdgcn_mfma_f32_32x32x16_bf16(ah[mt], Vh[ks][nn], accv[mt][nn], 0, 0, 0);
        }
    }
    __syncthreads();
  }
#undef STAGE2

  // epilogue: rowsum. C/D: col=lane&31, row=(r&3)+8*(r>>2)+4*hs (+mt*32).
  const int b = blockIdx.x >> 6;
  float qs[2], bkc[2], bvc[2];
#pragma unroll
  for (int nn = 0; nn < 2; ++nn) {
    int col = (w + 8 * nn) * 32 + l31;
    qs[nn] = q_sum[b * 512 + col];
    bkc[nn] = bk[col];
    bvc[nn] = bv[col];
  }
#pragma unroll
  for (int mt = 0; mt < 2; ++mt)
#pragma unroll
    for (int r = 0; r < 16; ++r) {
      float sk = ftanh(acck[mt][0][r] + bkc[0]) * qs[0] +
                 ftanh(acck[mt][1][r] + bkc[1]) * qs[1];
      float s_v = ftanh(accv[mt][0][r] + bvc[0]) +
                  ftanh(accv[mt][1][r] + bvc[1]);
#pragma unroll
      for (int off = 1; off <= 16; off <<= 1) {
        sk += __shfl_xor(sk, off);
        s_v += __shfl_xor(s_v, off);
      }
      if (l31 == 0) {
        int row = mt * 32 + (r & 3) + 8 * (r >> 2) + 4 * hs;
        redk[w][row] = sk;
        redv[w][row] = s_v;
      }
    }
  __syncthreads();
  if (tid < 64) {
    float s = 0.f;
#pragma unroll
    for (int j = 0; j < 8; ++j) s += redk[j][tid];
    scores[(size_t)blockIdx.x * 64 + tid] = s;
  } else if (tid < 128) {
    int r = tid - 64;
    float s = 0.f;
#pragma unroll
    for (int j = 0; j < 8; ++j) s += redv[j][r];
    sv[(size_t)blockIdx.x * 64 + r] = s;
  }
}

// q_sum[b][e] = sum of the batch's 32 row-block partials (BM=128)
__global__ void reduce_q(const float* __restrict__ qpart, float* __restrict__ q_sum) {
  int b = blockIdx.x;
  int e = threadIdx.x;
  const float* p = qpart + (size_t)b * 32 * 512 + e;
  float s = 0.f;
#pragma unroll
  for (int j = 0; j < 32; ++j) s += p[j * 512];
  q_sum[b * 512 + e] = s;
}

// per-batch masked softmax over scaled scores, times sv
__global__ void softmax_out(const float* __restrict__ scores,
                            const float* __restrict__ sv,
                            const int* __restrict__ lens,
                            float* __restrict__ out) {
  const int b = blockIdx.x;
  const int tid = threadIdx.x;  // 256
  const int lane = tid & 63, wid = tid >> 6;
  const int len = lens[b];
  const float scale = 0.04419417382415922f;  // 1/sqrt(512)
  __shared__ float sb[4];
  __shared__ float sb2[4];

  float sreg[16];
  const float* sc = scores + (size_t)b * 4096;
#pragma unroll
  for (int j = 0; j < 16; ++j) sreg[j] = sc[tid + j * 256] * scale;

  float m = -1e30f;
#pragma unroll
  for (int j = 0; j < 16; ++j)
    if (tid + j * 256 < len) m = fmaxf(m, sreg[j]);
#pragma unroll
  for (int off = 32; off >= 1; off >>= 1) m = fmaxf(m, __shfl_xor(m, off));
  if (lane == 0) sb[wid] = m;
  __syncthreads();
  m = fmaxf(fmaxf(sb[0], sb[1]), fmaxf(sb[2], sb[3]));

  float s = 0.f;
#pragma unroll
  for (int j = 0; j < 16; ++j)
    if (tid + j * 256 < len) s += expf(sreg[j] - m);
#pragma unroll
  for (int off = 32; off >= 1; off >>= 1) s += __shfl_xor(s, off);
  if (lane == 0) sb2[wid] = s;
  __syncthreads();
  const float inv = 1.f / (sb2[0] + sb2[1] + sb2[2] + sb2[3]);

  const float* svb = sv + (size_t)b * 4096;
  float* ob = out + (size_t)b * 4096;
#pragma unroll
  for (int j = 0; j < 16; ++j) {
    int l = tid + j * 256;
    ob[l] = (l < len) ? svb[l] * expf(sreg[j] - m) * inv : 0.0f;
  }
}

extern "C" void kernel_launch(void* const* d_in, const int* in_sizes, int n_in,
                              void* d_out, int out_size, void* d_ws, size_t ws_size,
                              hipStream_t stream) {
  const float* x  = (const float*)d_in[0];
  const float* Wk = (const float*)d_in[1];
  const float* bk = (const float*)d_in[2];
  const float* Wq = (const float*)d_in[3];
  const float* bq = (const float*)d_in[4];
  const float* Wv = (const float*)d_in[5];
  const float* bv = (const float*)d_in[6];
  const int* lens = (const int*)d_in[7];
  float* out = (float*)d_out;

  char* ws = (char*)d_ws;
  unsigned short* wfu = (unsigned short*)ws;
  const size_t WQ_HI = 0, WQ_LO = 262144;
  const size_t WK_HI = 524288, WK_LO = 786432;
  const size_t WV_HI = 1048576;
  float* qpart  = (float*)(ws + 3u * 1024 * 1024);                   // [512][512]
  float* q_sum  = (float*)(ws + 5u * 1024 * 1024);                   // [16][512]
  float* sv     = (float*)(ws + 5u * 1024 * 1024 + 32768);           // [16][4096]
  float* scores = (float*)(ws + 5u * 1024 * 1024 + 32768 + 262144);  // [16][4096]

  prep_kernel<<<384, 256, 0, stream>>>(Wq, Wk, Wv, wfu);
  pass1_q<<<512, 512, 0, stream>>>(x, wfu + WQ_HI, wfu + WQ_LO, bq, qpart);
  reduce_q<<<16, 512, 0, stream>>>(qpart, q_sum);
  pass2_kv<<<1024, 512, 0, stream>>>(x, wfu + WK_HI, wfu + WK_LO, wfu + WV_HI,
                                     bk, bv, q_sum, scores, sv);
  softmax_out<<<16, 256, 0, stream>>>(scores, sv, lens, out);
}

// Round 4
// 263.289 us; speedup vs baseline: 12.4020x; 1.0328x over previous
//
#include <hip/hip_runtime.h>
#include <hip/hip_bf16.h>
#include <math.h>

typedef __attribute__((ext_vector_type(8))) short short8;
typedef __attribute__((ext_vector_type(16))) float f32x16;
typedef __attribute__((ext_vector_type(4))) unsigned short us4;
typedef __attribute__((ext_vector_type(8))) unsigned short us8;

static __device__ __forceinline__ unsigned short bf16_rn(float f) {
  unsigned u = __float_as_uint(f);
  u += 0x7FFFu + ((u >> 16) & 1u);
  return (unsigned short)(u >> 16);
}
// split f into bf16 hi (round-nearest) + bf16 lo = rn(f - f32(hi)); hi+lo error ~2^-17
static __device__ __forceinline__ void cvt_hilo(float f, unsigned short& h, unsigned short& l) {
  unsigned u = __float_as_uint(f);
  unsigned hr = u + 0x7FFFu + ((u >> 16) & 1u);
  h = (unsigned short)(hr >> 16);
  l = bf16_rn(f - __uint_as_float(hr & 0xFFFF0000u));
}
// tanh(x) = 1 - 2/(e^{2x}+1); overflow-safe
static __device__ __forceinline__ float ftanh(float x) {
  float e = __builtin_amdgcn_exp2f(x * 2.885390081777927f);
  return 1.0f - 2.0f * __builtin_amdgcn_rcpf(e + 1.0f);
}

// ---------------------------------------------------------------------------
// Prep: pack Wq/Wk/Wv (f32 [512][512], W[e][d], K-contiguous) into 32x32x16
// MFMA-B-fragment order, bf16 hi/lo.
// value W[e = fn*32 + (lane&31)][d = gk*16 + (lane>>5)*8 + j]
//   at ushort index ((fn*32 + gk)*64 + lane)*8 + j ; fn:0..15, gk:0..31.
// Per matrix: hi at mat*524288, lo at +262144. mat: 0=Q,1=K,2=V.
// ---------------------------------------------------------------------------
__global__ void prep_kernel(const float* __restrict__ Wq,
                            const float* __restrict__ Wk,
                            const float* __restrict__ Wv,
                            unsigned short* __restrict__ ws_u16) {
  int id = blockIdx.x * 256 + threadIdx.x;  // 0..98303
  int mat = id >> 15;
  int rem = id & 32767;
  int fn = rem >> 11;
  int gk = (rem >> 6) & 31;
  int ln = rem & 63;
  int e  = fn * 32 + (ln & 31);
  int d0 = gk * 16 + ((ln >> 5) << 3);
  const float* W = (mat == 0) ? Wq : (mat == 1) ? Wk : Wv;
  unsigned short* oh = ws_u16 + (size_t)mat * 524288 + (size_t)rem * 8;
  unsigned short* ol = oh + 262144;
  const float* src = W + (size_t)e * 512 + d0;
#pragma unroll
  for (int j = 0; j < 8; ++j) {
    unsigned short h, l;
    cvt_hilo(src[j], h, l);
    oh[j] = h;
    ol[j] = l;
  }
}

// ---------------------------------------------------------------------------
// Pass 1: Q path. 128 rows x 512 cols per block, 8 waves 1Mx8N, 32x32x16 MFMA,
// 3-term hi/lo split. Triple-buffered LDS, ONE barrier per chunk; all global
// loads issued immediately AFTER the barrier (hipcc drains vmcnt(0) at every
// s_barrier -- loads must be a full chunk old when they hit the next drain).
// ---------------------------------------------------------------------------
__global__ __launch_bounds__(512, 2) void pass1_q(
    const float* __restrict__ x,
    const unsigned short* __restrict__ bh,
    const unsigned short* __restrict__ bl,
    const float* __restrict__ bias,
    float* __restrict__ qpart) {
  __shared__ unsigned short hib[3][128 * 40];   // row stride 40 ushorts (80 B)
  __shared__ unsigned short lob[3][128 * 40];

  const int tid = threadIdx.x;
  const int lane = tid & 63;
  const int w = tid >> 6;
  const int l31 = lane & 31, hs = lane >> 5;
  const int sr = tid >> 2, sc = (tid & 3) * 8;      // staging: 8 floats/thread
  const float* gxr = x + (size_t)blockIdx.x * 128 * 512 + (size_t)sr * 512 + sc;

  const int aoff = l31 * 40 + hs * 8;               // + mt*1280 + ks*16
  const unsigned short* bhp = bh + (size_t)w * 16384 + (size_t)lane * 8;
  const unsigned short* blp = bl + (size_t)w * 16384 + (size_t)lane * 8;

  f32x16 acc[4][2] = {};

#define STAGE1(BUFI, V0, V1)                                        \
  {                                                                 \
    float tf[8] = {(V0).x, (V0).y, (V0).z, (V0).w,                  \
                   (V1).x, (V1).y, (V1).z, (V1).w};                 \
    us8 hv, lv;                                                     \
    _Pragma("unroll")                                               \
    for (int j = 0; j < 8; ++j) {                                   \
      unsigned short hh, ll;                                        \
      cvt_hilo(tf[j], hh, ll);                                      \
      hv[j] = hh; lv[j] = ll;                                       \
    }                                                               \
    *(us8*)&hib[BUFI][sr * 40 + sc] = hv;                           \
    *(us8*)&lob[BUFI][sr * 40 + sc] = lv;                           \
  }

  // prologue: stage chunk 0 into buf0; chunk 1 into regs
  float4 xs0 = *(const float4*)(gxr);
  float4 xs1 = *(const float4*)(gxr + 4);
  STAGE1(0, xs0, xs1)
  xs0 = *(const float4*)(gxr + 32);
  xs1 = *(const float4*)(gxr + 36);

  int cur = 0;
#pragma unroll 1
  for (int c = 0; c < 16; ++c) {
    const int nxt = (cur == 2) ? 0 : cur + 1;
    __syncthreads();
    // B-fragment loads for this chunk -- issued right after the barrier
    short8 Bh[2][2], Bl[2][2];
#pragma unroll
    for (int ks = 0; ks < 2; ++ks)
#pragma unroll
      for (int nn = 0; nn < 2; ++nn) {
        const int go = nn * (8 * 16384) + (c * 2 + ks) * 512;
        Bh[ks][nn] = *(const short8*)(bhp + go);
        Bl[ks][nn] = *(const short8*)(blp + go);
      }
    // x prefetch for chunk c+2 (consumed next iteration; crosses one barrier
    // ~a full chunk after issue -> drain is free)
    float4 xn0 = xs0, xn1 = xs1;
    if (c < 14) {
      xn0 = *(const float4*)(gxr + (c + 2) * 32);
      xn1 = *(const float4*)(gxr + (c + 2) * 32 + 4);
    }
    // stage chunk c+1 into buf[nxt] (VALU work covers load latency)
    if (c < 15) { STAGE1(nxt, xs0, xs1) }

    const unsigned short* hc = &hib[cur][0];
    const unsigned short* lc = &lob[cur][0];
#pragma unroll
    for (int ks = 0; ks < 2; ++ks) {
      short8 ah[4], al[4];
#pragma unroll
      for (int mt = 0; mt < 4; ++mt) {
        ah[mt] = *(const short8*)(hc + aoff + mt * 1280 + ks * 16);
        al[mt] = *(const short8*)(lc + aoff + mt * 1280 + ks * 16);
      }
#pragma unroll
      for (int nn = 0; nn < 2; ++nn)
#pragma unroll
        for (int mt = 0; mt < 4; ++mt) {
          acc[mt][nn] = __builtin_amdgcn_mfma_f32_32x32x16_bf16(ah[mt], Bh[ks][nn], acc[mt][nn], 0, 0, 0);
          acc[mt][nn] = __builtin_amdgcn_mfma_f32_32x32x16_bf16(al[mt], Bh[ks][nn], acc[mt][nn], 0, 0, 0);
          acc[mt][nn] = __builtin_amdgcn_mfma_f32_32x32x16_bf16(ah[mt], Bl[ks][nn], acc[mt][nn], 0, 0, 0);
        }
    }
    xs0 = xn0; xs1 = xn1;
    cur = nxt;
  }
#undef STAGE1

  // epilogue: colsum of tanh. C/D: col=lane&31; 16 regs x 2 lane-halves = 32 rows.
  float cs[2];
#pragma unroll
  for (int nn = 0; nn < 2; ++nn) {
    float bc = bias[(w + 8 * nn) * 32 + l31];
    float s = 0.f;
#pragma unroll
    for (int mt = 0; mt < 4; ++mt)
#pragma unroll
      for (int r = 0; r < 16; ++r)
        s += ftanh(acc[mt][nn][r] + bc);
    s += __shfl_xor(s, 32);
    cs[nn] = s;
  }
  if (lane < 32) {
#pragma unroll
    for (int nn = 0; nn < 2; ++nn)
      qpart[(size_t)blockIdx.x * 512 + (w + 8 * nn) * 32 + l31] = cs[nn];
  }
}

// ---------------------------------------------------------------------------
// Pass 2: K (3-term split, rowsum weighted by q_sum) + V (1-term, rowsum),
// sharing x staging/A-frags. 64 rows x 512 cols, 8 waves 1Mx8N. Same
// triple-buffer / one-barrier-per-chunk schedule as pass 1.
// ---------------------------------------------------------------------------
__global__ __launch_bounds__(512, 2) void pass2_kv(
    const float* __restrict__ x,
    const unsigned short* __restrict__ kh,
    const unsigned short* __restrict__ kl,
    const unsigned short* __restrict__ vh,
    const float* __restrict__ bk,
    const float* __restrict__ bv,
    const float* __restrict__ q_sum,
    float* __restrict__ scores,
    float* __restrict__ sv) {
  __shared__ unsigned short hib[3][64 * 40];
  __shared__ unsigned short lob[3][64 * 40];
  __shared__ float redk[8][64];
  __shared__ float redv[8][64];

  const int tid = threadIdx.x;
  const int lane = tid & 63;
  const int w = tid >> 6;
  const int l31 = lane & 31, hs = lane >> 5;
  const int sr = tid >> 3, sc = (tid & 7) * 4;      // staging: 4 floats/thread
  const float* gxr = x + (size_t)blockIdx.x * 64 * 512 + (size_t)sr * 512 + sc;

  const int aoff = l31 * 40 + hs * 8;               // + mt*1280 + ks*16
  const unsigned short* khp = kh + (size_t)w * 16384 + (size_t)lane * 8;
  const unsigned short* klp = kl + (size_t)w * 16384 + (size_t)lane * 8;
  const unsigned short* vhp = vh + (size_t)w * 16384 + (size_t)lane * 8;

  f32x16 acck[2][2] = {};
  f32x16 accv[2][2] = {};

#define STAGE2(BUFI, V)                                             \
  {                                                                 \
    float tf[4] = {(V).x, (V).y, (V).z, (V).w};                     \
    us4 hv, lv;                                                     \
    _Pragma("unroll")                                               \
    for (int j = 0; j < 4; ++j) {                                   \
      unsigned short hh, ll;                                        \
      cvt_hilo(tf[j], hh, ll);                                      \
      hv[j] = hh; lv[j] = ll;                                       \
    }                                                               \
    *(us4*)&hib[BUFI][sr * 40 + sc] = hv;                           \
    *(us4*)&lob[BUFI][sr * 40 + sc] = lv;                           \
  }

  // prologue
  float4 xs = *(const float4*)(gxr);
  STAGE2(0, xs)
  xs = *(const float4*)(gxr + 32);

  int cur = 0;
#pragma unroll 1
  for (int c = 0; c < 16; ++c) {
    const int nxt = (cur == 2) ? 0 : cur + 1;
    __syncthreads();
    // B loads right after barrier
    short8 Kh[2][2], Kl[2][2], Vh[2][2];
#pragma unroll
    for (int ks = 0; ks < 2; ++ks)
#pragma unroll
      for (int nn = 0; nn < 2; ++nn) {
        const int go = nn * (8 * 16384) + (c * 2 + ks) * 512;
        Kh[ks][nn] = *(const short8*)(khp + go);
        Kl[ks][nn] = *(const short8*)(klp + go);
        Vh[ks][nn] = *(const short8*)(vhp + go);
      }
    float4 xn = xs;
    if (c < 14) { xn = *(const float4*)(gxr + (c + 2) * 32); }
    if (c < 15) { STAGE2(nxt, xs) }

    const unsigned short* hc = &hib[cur][0];
    const unsigned short* lc = &lob[cur][0];
#pragma unroll
    for (int ks = 0; ks < 2; ++ks) {
      short8 ah[2], al[2];
#pragma unroll
      for (int mt = 0; mt < 2; ++mt) {
        ah[mt] = *(const short8*)(hc + aoff + mt * 1280 + ks * 16);
        al[mt] = *(const short8*)(lc + aoff + mt * 1280 + ks * 16);
      }
#pragma unroll
      for (int nn = 0; nn < 2; ++nn)
#pragma unroll
        for (int mt = 0; mt < 2; ++mt) {
          acck[mt][nn] = __builtin_amdgcn_mfma_f32_32x32x16_bf16(ah[mt], Kh[ks][nn], acck[mt][nn], 0, 0, 0);
          acck[mt][nn] = __builtin_amdgcn_mfma_f32_32x32x16_bf16(al[mt], Kh[ks][nn], acck[mt][nn], 0, 0, 0);
          acck[mt][nn] = __builtin_amdgcn_mfma_f32_32x32x16_bf16(ah[mt], Kl[ks][nn], acck[mt][nn], 0, 0, 0);
          accv[mt][nn] = __builtin_amdgcn_mfma_f32_32x32x16_bf16(ah[mt], Vh[ks][nn], accv[mt][nn], 0, 0, 0);
        }
    }
    xs = xn;
    cur = nxt;
  }
#undef STAGE2

  // epilogue: rowsum. C/D: col=lane&31, row=(r&3)+8*(r>>2)+4*hs (+mt*32).
  const int b = blockIdx.x >> 6;
  float qs[2], bkc[2], bvc[2];
#pragma unroll
  for (int nn = 0; nn < 2; ++nn) {
    int col = (w + 8 * nn) * 32 + l31;
    qs[nn] = q_sum[b * 512 + col];
    bkc[nn] = bk[col];
    bvc[nn] = bv[col];
  }
#pragma unroll
  for (int mt = 0; mt < 2; ++mt)
#pragma unroll
    for (int r = 0; r < 16; ++r) {
      float sk = ftanh(acck[mt][0][r] + bkc[0]) * qs[0] +
                 ftanh(acck[mt][1][r] + bkc[1]) * qs[1];
      float s_v = ftanh(accv[mt][0][r] + bvc[0]) +
                  ftanh(accv[mt][1][r] + bvc[1]);
#pragma unroll
      for (int off = 1; off <= 16; off <<= 1) {
        sk += __shfl_xor(sk, off);
        s_v += __shfl_xor(s_v, off);
      }
      if (l31 == 0) {
        int row = mt * 32 + (r & 3) + 8 * (r >> 2) + 4 * hs;
        redk[w][row] = sk;
        redv[w][row] = s_v;
      }
    }
  __syncthreads();
  if (tid < 64) {
    float s = 0.f;
#pragma unroll
    for (int j = 0; j < 8; ++j) s += redk[j][tid];
    scores[(size_t)blockIdx.x * 64 + tid] = s;
  } else if (tid < 128) {
    int r = tid - 64;
    float s = 0.f;
#pragma unroll
    for (int j = 0; j < 8; ++j) s += redv[j][r];
    sv[(size_t)blockIdx.x * 64 + r] = s;
  }
}

// q_sum[b][e] = sum of the batch's 32 row-block partials (BM=128)
__global__ void reduce_q(const float* __restrict__ qpart, float* __restrict__ q_sum) {
  int b = blockIdx.x;
  int e = threadIdx.x;
  const float* p = qpart + (size_t)b * 32 * 512 + e;
  float s = 0.f;
#pragma unroll
  for (int j = 0; j < 32; ++j) s += p[j * 512];
  q_sum[b * 512 + e] = s;
}

// per-batch masked softmax over scaled scores, times sv
__global__ void softmax_out(const float* __restrict__ scores,
                            const float* __restrict__ sv,
                            const int* __restrict__ lens,
                            float* __restrict__ out) {
  const int b = blockIdx.x;
  const int tid = threadIdx.x;  // 256
  const int lane = tid & 63, wid = tid >> 6;
  const int len = lens[b];
  const float scale = 0.04419417382415922f;  // 1/sqrt(512)
  __shared__ float sb[4];
  __shared__ float sb2[4];

  float sreg[16];
  const float* sc = scores + (size_t)b * 4096;
#pragma unroll
  for (int j = 0; j < 16; ++j) sreg[j] = sc[tid + j * 256] * scale;

  float m = -1e30f;
#pragma unroll
  for (int j = 0; j < 16; ++j)
    if (tid + j * 256 < len) m = fmaxf(m, sreg[j]);
#pragma unroll
  for (int off = 32; off >= 1; off >>= 1) m = fmaxf(m, __shfl_xor(m, off));
  if (lane == 0) sb[wid] = m;
  __syncthreads();
  m = fmaxf(fmaxf(sb[0], sb[1]), fmaxf(sb[2], sb[3]));

  float s = 0.f;
#pragma unroll
  for (int j = 0; j < 16; ++j)
    if (tid + j * 256 < len) s += expf(sreg[j] - m);
#pragma unroll
  for (int off = 32; off >= 1; off >>= 1) s += __shfl_xor(s, off);
  if (lane == 0) sb2[wid] = s;
  __syncthreads();
  const float inv = 1.f / (sb2[0] + sb2[1] + sb2[2] + sb2[3]);

  const float* svb = sv + (size_t)b * 4096;
  float* ob = out + (size_t)b * 4096;
#pragma unroll
  for (int j = 0; j < 16; ++j) {
    int l = tid + j * 256;
    ob[l] = (l < len) ? svb[l] * expf(sreg[j] - m) * inv : 0.0f;
  }
}

extern "C" void kernel_launch(void* const* d_in, const int* in_sizes, int n_in,
                              void* d_out, int out_size, void* d_ws, size_t ws_size,
                              hipStream_t stream) {
  const float* x  = (const float*)d_in[0];
  const float* Wk = (const float*)d_in[1];
  const float* bk = (const float*)d_in[2];
  const float* Wq = (const float*)d_in[3];
  const float* bq = (const float*)d_in[4];
  const float* Wv = (const float*)d_in[5];
  const float* bv = (const float*)d_in[6];
  const int* lens = (const int*)d_in[7];
  float* out = (float*)d_out;

  char* ws = (char*)d_ws;
  unsigned short* wfu = (unsigned short*)ws;
  const size_t WQ_HI = 0, WQ_LO = 262144;
  const size_t WK_HI = 524288, WK_LO = 786432;
  const size_t WV_HI = 1048576;
  float* qpart  = (float*)(ws + 3u * 1024 * 1024);                   // [512][512]
  float* q_sum  = (float*)(ws + 5u * 1024 * 1024);                   // [16][512]
  float* sv     = (float*)(ws + 5u * 1024 * 1024 + 32768);           // [16][4096]
  float* scores = (float*)(ws + 5u * 1024 * 1024 + 32768 + 262144);  // [16][4096]

  prep_kernel<<<384, 256, 0, stream>>>(Wq, Wk, Wv, wfu);
  pass1_q<<<512, 512, 0, stream>>>(x, wfu + WQ_HI, wfu + WQ_LO, bq, qpart);
  reduce_q<<<16, 512, 0, stream>>>(qpart, q_sum);
  pass2_kv<<<1024, 512, 0, stream>>>(x, wfu + WK_HI, wfu + WK_LO, wfu + WV_HI,
                                     bk, bv, q_sum, scores, sv);
  softmax_out<<<16, 256, 0, stream>>>(scores, sv, lens, out);
}